// Round 15
// baseline (150.827 us; speedup 1.0000x reference)
//
#include <hip/hip_runtime.h>
#include <math.h>

#define W_IMG 2048
#define H_IMG 64
#define B_IMG 8
#define C_IMG 7
#define HW_IMG (H_IMG * W_IMG)
#define NPIX (B_IMG * HW_IMG)

typedef float v4f __attribute__((ext_vector_type(4)));
typedef int   v4i __attribute__((ext_vector_type(4)));

__device__ __forceinline__ float F(unsigned u) { return __uint_as_float(u); }
#define FMAF(a,b,c) __builtin_fmaf((a),(b),(c))
#define NTL(p) __builtin_nontemporal_load(p)

// ---------------------------------------------------------------------------
// EXACT path: bit-exact glibc (<=2.39) scalar s_atanf/e_atan2f (11-coeff
// fdlibm float port, op-by-op IEEE). DO NOT TOUCH (established R4-R9).
// ---------------------------------------------------------------------------
__device__ __forceinline__ float glibc_atanf(float x) {
    const float atanhi[4] = {F(0x3eed6338u), F(0x3f490fdau), F(0x3f7b985eu), F(0x3fc90fdau)};
    const float atanlo[4] = {F(0x31ac3769u), F(0x33222168u), F(0x33140fb4u), F(0x33a22168u)};
    const float aT0 = F(0x3eaaaaabu), aT1 = F(0xbe4ccccdu), aT2 = F(0x3e124925u),
                aT3 = F(0xbde38e38u), aT4 = F(0x3dba2e6eu), aT5 = F(0xbd9d8795u),
                aT6 = F(0x3d886b35u), aT7 = F(0xbd6ef16bu), aT8 = F(0x3d4bda59u),
                aT9 = F(0xbd15a221u), aT10 = F(0x3c8569d7u);

    unsigned hx = __float_as_uint(x);
    unsigned ix = hx & 0x7fffffffu;
    if (ix >= 0x4c800000u) {
        if (ix > 0x7f800000u) return x + x;
        float v = __fadd_rn(atanhi[3], atanlo[3]);
        return (hx >> 31) ? -v : v;
    }
    int id;
    float xr = x;
    if (ix < 0x3ee00000u) {
        if (ix < 0x31000000u) return x;
        id = -1;
    } else {
        xr = fabsf(x);
        if (ix < 0x3f980000u) {
            if (ix < 0x3f300000u) {
                id = 0;
                xr = __fdiv_rn(__fsub_rn(__fmul_rn(2.0f, xr), 1.0f),
                               __fadd_rn(2.0f, xr));
            } else {
                id = 1;
                xr = __fdiv_rn(__fsub_rn(xr, 1.0f), __fadd_rn(xr, 1.0f));
            }
        } else {
            if (ix < 0x401c0000u) {
                id = 2;
                xr = __fdiv_rn(__fsub_rn(xr, 1.5f),
                               __fadd_rn(1.0f, __fmul_rn(1.5f, xr)));
            } else {
                id = 3;
                xr = __fdiv_rn(-1.0f, xr);
            }
        }
    }
    float z = __fmul_rn(xr, xr);
    float w = __fmul_rn(z, z);
    float s1 = __fmul_rn(z, __fadd_rn(aT0, __fmul_rn(w, __fadd_rn(aT2,
               __fmul_rn(w, __fadd_rn(aT4, __fmul_rn(w, __fadd_rn(aT6,
               __fmul_rn(w, __fadd_rn(aT8, __fmul_rn(w, aT10)))))))))));
    float s2 = __fmul_rn(w, __fadd_rn(aT1, __fmul_rn(w, __fadd_rn(aT3,
               __fmul_rn(w, __fadd_rn(aT5, __fmul_rn(w, __fadd_rn(aT7,
               __fmul_rn(w, aT9)))))))));
    if (id < 0) return __fsub_rn(x, __fmul_rn(x, __fadd_rn(s1, s2)));
    float zz = __fsub_rn(atanhi[id],
               __fsub_rn(__fsub_rn(__fmul_rn(xr, __fadd_rn(s1, s2)), atanlo[id]), xr));
    return (hx >> 31) ? -zz : zz;
}

__device__ __forceinline__ float glibc_atan2f(float y, float x) {
    const float pi_o_2 = F(0x3fc90fdbu);
    const float pi     = F(0x40490fdbu);
    const float pi_lo  = F(0xb3bbbd2eu);
    unsigned hx = __float_as_uint(x), hy = __float_as_uint(y);
    unsigned ix = hx & 0x7fffffffu, iy = hy & 0x7fffffffu;
    if (ix > 0x7f800000u || iy > 0x7f800000u) return x + y;
    if (hx == 0x3f800000u) return glibc_atanf(y);
    unsigned m = ((hy >> 31) & 1u) | ((hx >> 30) & 2u);
    if (iy == 0) {
        switch (m) {
            case 0: case 1: return y;
            case 2: return pi;
            default: return -pi;
        }
    }
    if (ix == 0) return (m & 1u) ? -pi_o_2 : pi_o_2;
    if (ix == 0x7f800000u) {
        if (iy == 0x7f800000u) {
            switch (m) {
                case 0: return F(0x3f490fdbu);
                case 1: return -F(0x3f490fdbu);
                case 2: return __fmul_rn(3.0f, F(0x3f490fdbu));
                default: return -__fmul_rn(3.0f, F(0x3f490fdbu));
            }
        } else {
            switch (m) {
                case 0: return 0.0f;
                case 1: return -0.0f;
                case 2: return pi;
                default: return -pi;
            }
        }
    }
    if (iy == 0x7f800000u) return (m & 1u) ? -pi_o_2 : pi_o_2;

    int k = ((int)iy - (int)ix) >> 23;
    float z;
    if (k > 26) {
        z = __fadd_rn(pi_o_2, __fmul_rn(0.5f, pi_lo));
        m &= 1u;
    } else if (k < -26 && (hx >> 31)) {
        z = 0.0f;
    } else {
        z = glibc_atanf(fabsf(__fdiv_rn(y, x)));
    }
    switch (m) {
        case 0: return z;
        case 1: return __uint_as_float(__float_as_uint(z) ^ 0x80000000u);
        case 2: return __fsub_rn(pi, __fsub_rn(z, pi_lo));
        default: return __fsub_rn(__fsub_rn(z, pi_lo), pi);
    }
}

struct Proj {
    float theta, phi;
    int   pix;
    bool  in_image;
};

#define H0F   ((float)(-3.14159265358979323846))
#define SPANH ((float)( 6.28318530717958647692))
#define V0F   ((float)(-3.0 * 3.14159265358979323846 / 180.0))
#define SPANV ((float)((25.0 * 3.14159265358979323846 / 180.0) - \
                       (-3.0 * 3.14159265358979323846 / 180.0)))
#define RHc   (1.0f / SPANH)
#define RVc   (1.0f / SPANV)

__device__ __forceinline__ Proj project_exact(float x, float y, float zr, float bsf) {
    Proj p;
    p.theta = -glibc_atan2f(y, x);
    float s  = __fsqrt_rn(FMAF(-zr, zr, 1.0f));
    float d  = __fadd_rn(1.0f, s);
    p.phi = -__fmul_rn(2.0f, glibc_atan2f(zr, d));

    float u_n = __fmul_rn(__fsub_rn(p.theta, H0F), RHc);
    float v_n = __fmul_rn(__fsub_rn(p.phi,   V0F), RVc);
    p.in_image = (u_n >= 0.0f) && (u_n < 1.0f) && (v_n >= 0.0f) && (v_n < 1.0f);
    p.pix = -1;
    if (p.in_image) {
        int u = (int)__fmul_rn(u_n, (float)W_IMG);
        int v = (int)__fmul_rn(v_n, (float)H_IMG);
        int b = (int)bsf;
        if (u < W_IMG && v < H_IMG) {
            p.pix = (b * H_IMG + v) * W_IMG + u;
        } else {
            p.in_image = false;
        }
    }
    return p;
}

__device__ __forceinline__ float norm_r(float x, float y, float z) {
    return __fsqrt_rn(FMAF(z, z, FMAF(y, y, __fmul_rn(x, x))));
}

// FAST path: minimax atan on [0,1] (|err| <~ 2.4e-5 rad), for bin-margin test
// and output features (threshold 3.02 >> 2.4e-5).
__device__ __forceinline__ float atan01(float t) {
    float q = t * t;
    float p =          -0.0117212f;
    p = FMAF(q, p,      0.05265332f);
    p = FMAF(q, p,     -0.11643287f);
    p = FMAF(q, p,      0.19354346f);
    p = FMAF(q, p,     -0.33262347f);
    p = FMAF(q, p,      0.99997726f);
    return t * p;
}

__device__ __forceinline__ void fast_angles(float x, float y, float zr,
                                            float* theta, float* phi) {
    float ax = fabsf(x), ay = fabsf(y);
    float mx = fmaxf(ax, ay), mn = fminf(ax, ay);
    float t = (mx > 0.0f) ? (mn / mx) : 0.0f;
    float a = atan01(t);
    if (ay > ax) a = 1.57079632679f - a;
    if (x < 0.0f) a = 3.14159265359f - a;
    *theta = (y < 0.0f) ? a : -a;               // == -atan2(y,x)

    float az  = fabsf(zr);
    float arg = az / __fsqrt_rn(FMAF(-zr, zr, 1.0f));
    float pa  = atan01(arg);
    *phi = (zr >= 0.0f) ? -pa : pa;             // == -asin(zr)
}

#define MU 0.06f
#define MV 0.025f

// 1 point/thread, reverse order, monotone stale-read filter.
// Point loads are NONTEMPORAL (nt = evict-first): the 40 MB point stream must
// not thrash the 2 MB winner array out of each XCD's 4 MB L2 — the filter
// read and atomic line fetches should stay L2-hit (R13 FETCH=73MB showed
// ~33MB of winner refetch from HBM).
__global__ void __launch_bounds__(256)
scatter_winner(const float* __restrict__ pts, int* __restrict__ winner, int n) {
    int t = blockIdx.x * blockDim.x + threadIdx.x;
    if (t >= n) return;
    int i = n - 1 - t;
    const float* q = pts + (size_t)i * 5;
    float bsf = NTL(q + 0);
    float x   = NTL(q + 1);
    float y   = NTL(q + 2);
    float z   = NTL(q + 3);

    float r  = norm_r(x, y, z);
    float zr = __fdiv_rn(z, fmaxf(r, 1e-5f));
    if (zr > 0.05240f || zr < -0.42270f) return;   // guaranteed v-reject

    float th_a, ph_a;
    fast_angles(x, y, zr, &th_a, &ph_a);
    float uf = (th_a - H0F) * (RHc * (float)W_IMG);
    float vf = (ph_a - V0F) * (RVc * (float)H_IMG);
    float ulo = floorf(uf - MU), uhi = floorf(uf + MU);
    float vlo = floorf(vf - MV), vhi = floorf(vf + MV);

    int pix;
    if (ulo == uhi && vlo == vhi) {
        int u = (int)ulo, v = (int)vlo;
        if (u < 0 || u >= W_IMG || v < 0 || v >= H_IMG) return;
        pix = ((int)bsf * H_IMG + v) * W_IMG + u;
    } else {
        Proj p = project_exact(x, y, zr, bsf);
        if (!p.in_image) return;
        pix = p.pix;
    }

    if (winner[pix] >= i) return;     // monotone filter (stale-safe, L2-hit)
    atomicMax(&winner[pix], i);
}

// 4 pixels/thread: NT v4i winner load (streamed once), batched gathers
// (cached), fast features, 7 NT float4 channel stores.
__global__ void __launch_bounds__(256, 4)
write_output(const float* __restrict__ pts, const int* __restrict__ winner,
             float* __restrict__ out) {
    int t  = blockIdx.x * blockDim.x + threadIdx.x;
    int p0 = t * 4;
    if (p0 >= NPIX) return;

    v4i w4 = NTL((const v4i*)(winner + p0));
    int wis[4] = {w4.x, w4.y, w4.z, w4.w};

    float qx[4], qy[4], qz[4], qi[4];
#pragma unroll
    for (int k = 0; k < 4; ++k) {
        if (wis[k] >= 0) {
            const float* q = pts + (size_t)wis[k] * 5;
            qx[k] = q[1]; qy[k] = q[2]; qz[k] = q[3]; qi[k] = q[4];
        }
    }

    float fc[C_IMG][4];
#pragma unroll
    for (int c = 0; c < C_IMG; ++c)
#pragma unroll
        for (int k = 0; k < 4; ++k) fc[c][k] = 0.f;

#pragma unroll
    for (int k = 0; k < 4; ++k) {
        if (wis[k] >= 0) {
            float x = qx[k], y = qy[k], z = qz[k];
            float r  = norm_r(x, y, z);
            float zr = __fdiv_rn(z, fmaxf(r, 1e-5f));
            float th, ph;
            fast_angles(x, y, zr, &th, &ph);
            fc[0][k] = x; fc[1][k] = y; fc[2][k] = z;
            fc[3][k] = r; fc[4][k] = th; fc[5][k] = ph;
            fc[6][k] = qi[k];
        }
    }

    int b  = p0 >> 17;             // / HW_IMG (131072)
    int hw = p0 & (HW_IMG - 1);
    size_t base = (size_t)b * C_IMG * HW_IMG + hw;
#pragma unroll
    for (int c = 0; c < C_IMG; ++c) {
        v4f v = {fc[c][0], fc[c][1], fc[c][2], fc[c][3]};
        __builtin_nontemporal_store(v, (v4f*)(out + base + (size_t)c * HW_IMG));
    }
}

extern "C" void kernel_launch(void* const* d_in, const int* in_sizes, int n_in,
                              void* d_out, int out_size, void* d_ws, size_t ws_size,
                              hipStream_t stream) {
    const float* pts = (const float*)d_in[0];
    int n = in_sizes[0] / 5;
    int* winner = (int*)d_ws;   // 0xAA-poisoned each launch = negative = empty
    float* out = (float*)d_out;

    scatter_winner<<<(n + 255) / 256, 256, 0, stream>>>(pts, winner, n);

    int pthreads = NPIX / 4;
    write_output<<<(pthreads + 255) / 256, 256, 0, stream>>>(pts, winner, out);
}

// Round 17
// 147.851 us; speedup vs baseline: 1.0201x; 1.0201x over previous
//
#include <hip/hip_runtime.h>
#include <math.h>

#define W_IMG 2048
#define H_IMG 64
#define B_IMG 8
#define C_IMG 7
#define HW_IMG (H_IMG * W_IMG)
#define NPIX (B_IMG * HW_IMG)

typedef float v4f __attribute__((ext_vector_type(4)));
typedef int   v4i __attribute__((ext_vector_type(4)));

__device__ __forceinline__ float F(unsigned u) { return __uint_as_float(u); }
#define FMAF(a,b,c) __builtin_fmaf((a),(b),(c))

// ---------------------------------------------------------------------------
// EXACT path: bit-exact glibc (<=2.39) scalar s_atanf/e_atan2f (11-coeff
// fdlibm float port, op-by-op IEEE). DO NOT TOUCH (established R4-R9).
// ---------------------------------------------------------------------------
__device__ __forceinline__ float glibc_atanf(float x) {
    const float atanhi[4] = {F(0x3eed6338u), F(0x3f490fdau), F(0x3f7b985eu), F(0x3fc90fdau)};
    const float atanlo[4] = {F(0x31ac3769u), F(0x33222168u), F(0x33140fb4u), F(0x33a22168u)};
    const float aT0 = F(0x3eaaaaabu), aT1 = F(0xbe4ccccdu), aT2 = F(0x3e124925u),
                aT3 = F(0xbde38e38u), aT4 = F(0x3dba2e6eu), aT5 = F(0xbd9d8795u),
                aT6 = F(0x3d886b35u), aT7 = F(0xbd6ef16bu), aT8 = F(0x3d4bda59u),
                aT9 = F(0xbd15a221u), aT10 = F(0x3c8569d7u);

    unsigned hx = __float_as_uint(x);
    unsigned ix = hx & 0x7fffffffu;
    if (ix >= 0x4c800000u) {
        if (ix > 0x7f800000u) return x + x;
        float v = __fadd_rn(atanhi[3], atanlo[3]);
        return (hx >> 31) ? -v : v;
    }
    int id;
    float xr = x;
    if (ix < 0x3ee00000u) {
        if (ix < 0x31000000u) return x;
        id = -1;
    } else {
        xr = fabsf(x);
        if (ix < 0x3f980000u) {
            if (ix < 0x3f300000u) {
                id = 0;
                xr = __fdiv_rn(__fsub_rn(__fmul_rn(2.0f, xr), 1.0f),
                               __fadd_rn(2.0f, xr));
            } else {
                id = 1;
                xr = __fdiv_rn(__fsub_rn(xr, 1.0f), __fadd_rn(xr, 1.0f));
            }
        } else {
            if (ix < 0x401c0000u) {
                id = 2;
                xr = __fdiv_rn(__fsub_rn(xr, 1.5f),
                               __fadd_rn(1.0f, __fmul_rn(1.5f, xr)));
            } else {
                id = 3;
                xr = __fdiv_rn(-1.0f, xr);
            }
        }
    }
    float z = __fmul_rn(xr, xr);
    float w = __fmul_rn(z, z);
    float s1 = __fmul_rn(z, __fadd_rn(aT0, __fmul_rn(w, __fadd_rn(aT2,
               __fmul_rn(w, __fadd_rn(aT4, __fmul_rn(w, __fadd_rn(aT6,
               __fmul_rn(w, __fadd_rn(aT8, __fmul_rn(w, aT10)))))))))));
    float s2 = __fmul_rn(w, __fadd_rn(aT1, __fmul_rn(w, __fadd_rn(aT3,
               __fmul_rn(w, __fadd_rn(aT5, __fmul_rn(w, __fadd_rn(aT7,
               __fmul_rn(w, aT9)))))))));
    if (id < 0) return __fsub_rn(x, __fmul_rn(x, __fadd_rn(s1, s2)));
    float zz = __fsub_rn(atanhi[id],
               __fsub_rn(__fsub_rn(__fmul_rn(xr, __fadd_rn(s1, s2)), atanlo[id]), xr));
    return (hx >> 31) ? -zz : zz;
}

__device__ __forceinline__ float glibc_atan2f(float y, float x) {
    const float pi_o_2 = F(0x3fc90fdbu);
    const float pi     = F(0x40490fdbu);
    const float pi_lo  = F(0xb3bbbd2eu);
    unsigned hx = __float_as_uint(x), hy = __float_as_uint(y);
    unsigned ix = hx & 0x7fffffffu, iy = hy & 0x7fffffffu;
    if (ix > 0x7f800000u || iy > 0x7f800000u) return x + y;
    if (hx == 0x3f800000u) return glibc_atanf(y);
    unsigned m = ((hy >> 31) & 1u) | ((hx >> 30) & 2u);
    if (iy == 0) {
        switch (m) {
            case 0: case 1: return y;
            case 2: return pi;
            default: return -pi;
        }
    }
    if (ix == 0) return (m & 1u) ? -pi_o_2 : pi_o_2;
    if (ix == 0x7f800000u) {
        if (iy == 0x7f800000u) {
            switch (m) {
                case 0: return F(0x3f490fdbu);
                case 1: return -F(0x3f490fdbu);
                case 2: return __fmul_rn(3.0f, F(0x3f490fdbu));
                default: return -__fmul_rn(3.0f, F(0x3f490fdbu));
            }
        } else {
            switch (m) {
                case 0: return 0.0f;
                case 1: return -0.0f;
                case 2: return pi;
                default: return -pi;
            }
        }
    }
    if (iy == 0x7f800000u) return (m & 1u) ? -pi_o_2 : pi_o_2;

    int k = ((int)iy - (int)ix) >> 23;
    float z;
    if (k > 26) {
        z = __fadd_rn(pi_o_2, __fmul_rn(0.5f, pi_lo));
        m &= 1u;
    } else if (k < -26 && (hx >> 31)) {
        z = 0.0f;
    } else {
        z = glibc_atanf(fabsf(__fdiv_rn(y, x)));
    }
    switch (m) {
        case 0: return z;
        case 1: return __uint_as_float(__float_as_uint(z) ^ 0x80000000u);
        case 2: return __fsub_rn(pi, __fsub_rn(z, pi_lo));
        default: return __fsub_rn(__fsub_rn(z, pi_lo), pi);
    }
}

struct Proj {
    float theta, phi;
    int   pix;
    bool  in_image;
};

#define H0F   ((float)(-3.14159265358979323846))
#define SPANH ((float)( 6.28318530717958647692))
#define V0F   ((float)(-3.0 * 3.14159265358979323846 / 180.0))
#define SPANV ((float)((25.0 * 3.14159265358979323846 / 180.0) - \
                       (-3.0 * 3.14159265358979323846 / 180.0)))
#define RHc   (1.0f / SPANH)
#define RVc   (1.0f / SPANV)

__device__ __forceinline__ Proj project_exact(float x, float y, float zr, float bsf) {
    Proj p;
    p.theta = -glibc_atan2f(y, x);
    float s  = __fsqrt_rn(FMAF(-zr, zr, 1.0f));
    float d  = __fadd_rn(1.0f, s);
    p.phi = -__fmul_rn(2.0f, glibc_atan2f(zr, d));

    float u_n = __fmul_rn(__fsub_rn(p.theta, H0F), RHc);
    float v_n = __fmul_rn(__fsub_rn(p.phi,   V0F), RVc);
    p.in_image = (u_n >= 0.0f) && (u_n < 1.0f) && (v_n >= 0.0f) && (v_n < 1.0f);
    p.pix = -1;
    if (p.in_image) {
        int u = (int)__fmul_rn(u_n, (float)W_IMG);
        int v = (int)__fmul_rn(v_n, (float)H_IMG);
        int b = (int)bsf;
        if (u < W_IMG && v < H_IMG) {
            p.pix = (b * H_IMG + v) * W_IMG + u;
        } else {
            p.in_image = false;
        }
    }
    return p;
}

__device__ __forceinline__ float norm_r(float x, float y, float z) {
    return __fsqrt_rn(FMAF(z, z, FMAF(y, y, __fmul_rn(x, x))));
}

// ---------------------------------------------------------------------------
// FAST path: OCML device atan2f (ROCm libm, documented <= 2 ulp — a
// TRUSTWORTHY bound, unlike R16's invented poly). Binning arithmetic is the
// IDENTICAL op chain as project_exact, so fast-vs-exact bin deviation comes
// only through theta/phi: |dTheta| <= 4 ulp(pi) ~ 1e-6 rad -> du <= 3.3e-4
// bins; |dPhi| <= 4 ulp(0.45) ~ 1.2e-7 rad -> dv <= 1.6e-5 bins.
// ---------------------------------------------------------------------------
#define MU 0.002f    // 6x the justified u deviation bound
#define MV 0.0004f   // 25x the justified v deviation bound

// 1 point/thread, reverse order (winners land first), monotone stale-read
// filter; winner slot prefetched before the ambiguity decision.
__global__ void __launch_bounds__(256)
scatter_winner(const float* __restrict__ pts, int* __restrict__ winner, int n) {
    int t = blockIdx.x * blockDim.x + threadIdx.x;
    if (t >= n) return;
    int i = n - 1 - t;
    const float* q = pts + (size_t)i * 5;
    float bsf = q[0], x = q[1], y = q[2], z = q[3];

    float r  = norm_r(x, y, z);
    float zr = __fdiv_rn(z, fmaxf(r, 1e-5f));
    if (zr > 0.05240f || zr < -0.42270f) return;   // guaranteed v-reject (R12+)

    // Fast angles (OCML, <=2 ulp each).
    float th = -atan2f(y, x);
    float s  = __fsqrt_rn(FMAF(-zr, zr, 1.0f));
    float d  = __fadd_rn(1.0f, s);
    float ph = -__fmul_rn(2.0f, atan2f(zr, d));

    // Binning: IDENTICAL op chain to project_exact.
    float u_n = __fmul_rn(__fsub_rn(th, H0F), RHc);
    float v_n = __fmul_rn(__fsub_rn(ph, V0F), RVc);
    float uf  = __fmul_rn(u_n, (float)W_IMG);
    float vf  = __fmul_rn(v_n, (float)H_IMG);

    // Ambiguity: within margin of ANY integer boundary (covers both the bin
    // edges and the u_n in {0,1} / v_n in {0,1} image edges, = uf in {0,W}).
    float fu = uf - floorf(uf);
    float fv = vf - floorf(vf);
    bool amb = (fu < MU) | (fu > 1.0f - MU) | (fv < MV) | (fv > 1.0f - MV);

    bool in_img = (u_n >= 0.0f) & (u_n < 1.0f) & (v_n >= 0.0f) & (v_n < 1.0f);
    int u = (int)uf, v = (int)vf;          // trunc; valid when in_img
    int pix_fast = ((int)bsf * H_IMG + v) * W_IMG + u;
    // Prefetch the (almost certainly final) winner slot.
    int w_pre = (in_img & !amb) ? winner[pix_fast] : -1;

    int pix;
    if (!amb) {
        if (!in_img) return;                       // provably out of image
        if (u >= W_IMG || v >= H_IMG) return;      // mode='drop' guard
        pix = pix_fast;
        if (w_pre >= i) return;                    // monotone filter
    } else {
        Proj p = project_exact(x, y, zr, bsf);     // boundary: exact decides
        if (!p.in_image) return;
        pix = p.pix;
        if (winner[pix] >= i) return;
    }
    atomicMax(&winner[pix], i);
}

// 8 pixels/thread: two v4i winner loads, 8-deep gather MLP, OCML features
// (err ~1e-7 << 3.02 threshold), 14 NT v4f channel stores.
__global__ void __launch_bounds__(256, 4)
write_output(const float* __restrict__ pts, const int* __restrict__ winner,
             float* __restrict__ out) {
    int t  = blockIdx.x * blockDim.x + threadIdx.x;
    int p0 = t * 8;
    if (p0 >= NPIX) return;

    v4i wa = *(const v4i*)(winner + p0);
    v4i wb = *(const v4i*)(winner + p0 + 4);
    int wis[8] = {wa.x, wa.y, wa.z, wa.w, wb.x, wb.y, wb.z, wb.w};

    float qx[8], qy[8], qz[8], qi[8];
#pragma unroll
    for (int k = 0; k < 8; ++k) {
        if (wis[k] >= 0) {
            const float* q = pts + (size_t)wis[k] * 5;
            qx[k] = q[1]; qy[k] = q[2]; qz[k] = q[3]; qi[k] = q[4];
        }
    }

    float fc[C_IMG][8];
#pragma unroll
    for (int c = 0; c < C_IMG; ++c)
#pragma unroll
        for (int k = 0; k < 8; ++k) fc[c][k] = 0.f;

#pragma unroll
    for (int k = 0; k < 8; ++k) {
        if (wis[k] >= 0) {
            float x = qx[k], y = qy[k], z = qz[k];
            float r  = norm_r(x, y, z);
            float zr = __fdiv_rn(z, fmaxf(r, 1e-5f));
            float th = -atan2f(y, x);
            float s  = __fsqrt_rn(FMAF(-zr, zr, 1.0f));
            float dd = __fadd_rn(1.0f, s);
            float ph = -__fmul_rn(2.0f, atan2f(zr, dd));
            fc[0][k] = x; fc[1][k] = y; fc[2][k] = z;
            fc[3][k] = r; fc[4][k] = th; fc[5][k] = ph;
            fc[6][k] = qi[k];
        }
    }

    int b  = p0 >> 17;             // / HW_IMG (131072)
    int hw = p0 & (HW_IMG - 1);
    size_t base = (size_t)b * C_IMG * HW_IMG + hw;
#pragma unroll
    for (int c = 0; c < C_IMG; ++c) {
        v4f va = {fc[c][0], fc[c][1], fc[c][2], fc[c][3]};
        v4f vb = {fc[c][4], fc[c][5], fc[c][6], fc[c][7]};
        __builtin_nontemporal_store(va, (v4f*)(out + base + (size_t)c * HW_IMG));
        __builtin_nontemporal_store(vb, (v4f*)(out + base + (size_t)c * HW_IMG + 4));
    }
}

extern "C" void kernel_launch(void* const* d_in, const int* in_sizes, int n_in,
                              void* d_out, int out_size, void* d_ws, size_t ws_size,
                              hipStream_t stream) {
    const float* pts = (const float*)d_in[0];
    int n = in_sizes[0] / 5;
    int* winner = (int*)d_ws;   // 0xAA-poisoned each launch = negative = empty
    float* out = (float*)d_out;

    scatter_winner<<<(n + 255) / 256, 256, 0, stream>>>(pts, winner, n);

    int pthreads = NPIX / 8;
    write_output<<<(pthreads + 255) / 256, 256, 0, stream>>>(pts, winner, out);
}